// Round 7
// baseline (165.748 us; speedup 1.0000x reference)
//
#include <hip/hip_runtime.h>
#include <cstdint>
#include <cstddef>

// ---------------------------------------------------------------------------
// SparseAttention (DeepSpeed-style block-sparse causal attention)
//   x[2,2048,1024] @ w_qkv[1024,3072] -> q,k [bh][n][d], v blocked (bf16)
//   block-sparse flash attention (16x16 blocks, layout[128,128], causal)
//   attn_out[4096,1024] @ w_out[1024,1024] + b_out -> out (fp32)
// R14: clean A/B — GEMMs identical to R13 (conflict-free swizzle, measured
//      164.4 us); attn reverted to the R9 block (LDS pbuf P^T permute +
//      rotate pipeline) keeping R9's cvt_pk/exp2/setprio. Isolates the R10
//      permlane+unroll attn block, which coincided with a +4.1 us move.
// ---------------------------------------------------------------------------

typedef short bf8 __attribute__((ext_vector_type(8)));   // 8 bf16 payloads (4 VGPRs)
typedef float f32x4 __attribute__((ext_vector_type(4)));
typedef unsigned short u16;
typedef unsigned int u32;

#define MFMA_BF16(a, b, c) __builtin_amdgcn_mfma_f32_16x16x32_bf16((a), (b), (c), 0, 0, 0)

constexpr int SEQ = 2048;
constexpr int NH = 16;
constexpr int DHD = 64;
constexpr int NBLK = 128;
constexpr int DIM = 1024;

// hw packed fp32->bf16 convert (RNE), a -> low 16, b -> high 16
__device__ __forceinline__ u32 pack2bf(float a, float b) {
  u32 r;
  asm("v_cvt_pk_bf16_f32 %0, %1, %2" : "=v"(r) : "v"(a), "v"(b));
  return r;
}
__device__ __forceinline__ void gload_lds16(const u16* g, u16* l) {
  auto gp = (const __attribute__((address_space(1))) u16*)(g);
  auto lp = (__attribute__((address_space(3))) u16*)(l);
  __builtin_amdgcn_global_load_lds(gp, lp, 16, 0, 0);
}

// ---------------------------------------------------------------------------
// 1) fused prep: [0,2048) convert x; [2048,2816) transpose w_qkv;
//    [2816,3072) transpose w_out; [3072,3104) build layout lists.
// ---------------------------------------------------------------------------
__global__ __launch_bounds__(256) void prep(
    const float* __restrict__ x, u16* __restrict__ xbf,
    const float* __restrict__ wqkv, u16* __restrict__ wqkvT,
    const float* __restrict__ wout, u16* __restrict__ woutT,
    const unsigned char* __restrict__ lay,
    int* __restrict__ cnt, int* __restrict__ cols) {
  __shared__ u16 tile[64][72];
  int bid = blockIdx.x;
  int t = threadIdx.x;

  if (bid < 2048) {                       // ---- convert x fp32 -> bf16
    int idx = (bid * 256 + t) * 8;
    float4 a = *(const float4*)(x + idx);
    float4 b = *(const float4*)(x + idx + 4);
    *(uint4*)(xbf + idx) = make_uint4(pack2bf(a.x, a.y), pack2bf(a.z, a.w),
                                      pack2bf(b.x, b.y), pack2bf(b.z, b.w));
    return;
  }
  bid -= 2048;
  if (bid < 768 + 256) {                  // ---- weight transposes
    const float* in; u16* out; int C, bx, by;
    if (bid < 768) { in = wqkv; out = wqkvT; C = 3072; bx = bid % 48; by = bid / 48; }
    else { int r = bid - 768; in = wout; out = woutT; C = 1024; bx = r % 16; by = r / 16; }
    const int R = 1024;
    int c0 = bx * 64, r0 = by * 64;
    int rr = t >> 4, cc = (t & 15) * 4;
    #pragma unroll
    for (int p = 0; p < 64; p += 16) {
      float4 v = *(const float4*)(in + (size_t)(r0 + rr + p) * C + c0 + cc);
      *(u32*)&tile[rr + p][cc + 0] = pack2bf(v.x, v.y);
      *(u32*)&tile[rr + p][cc + 2] = pack2bf(v.z, v.w);
    }
    __syncthreads();
    int oc = t >> 3, orr = (t & 7) * 8;
    #pragma unroll
    for (int p = 0; p < 64; p += 32) {
      u16 tmp[8];
      #pragma unroll
      for (int qy = 0; qy < 8; qy++) tmp[qy] = tile[orr + qy][oc + p];
      u16* dst = out + (size_t)(c0 + oc + p) * R + r0 + orr;
      *(ushort4*)(dst)     = make_ushort4(tmp[0], tmp[1], tmp[2], tmp[3]);
      *(ushort4*)(dst + 4) = make_ushort4(tmp[4], tmp[5], tmp[6], tmp[7]);
    }
    return;
  }
  bid -= 1024;                            // ---- build_lists: 32 blocks x 4 waves
  int wave = t >> 6, lane = t & 63;
  int i = bid * 4 + wave;                 // block row
  const uint4* l4 = (const uint4*)lay;
  u32 acc = 0;
  #pragma unroll
  for (int it = 0; it < 16; it++) {
    uint4 v = l4[it * 64 + lane];
    acc |= ((v.x | v.y | v.z | v.w) & 0xFFFFFF00u);
  }
  bool as_int32 = (__ballot(acc != 0) == 0ULL);  // int32-encoded 0/1 detection
  const int* li = (const int*)lay;
  int j0 = lane, j1 = lane + 64;
  bool p0 = (j0 <= i) && (as_int32 ? (li[i * 128 + j0] != 0) : (lay[i * 128 + j0] != 0));
  bool p1 = (j1 <= i) && (as_int32 ? (li[i * 128 + j1] != 0) : (lay[i * 128 + j1] != 0));
  unsigned long long m0 = __ballot(p0), m1 = __ballot(p1);
  unsigned long long lt = (1ULL << lane) - 1ULL;
  int base0 = __popcll(m0);
  if (p0) cols[i * 128 + __popcll(m0 & lt)] = j0;
  if (p1) cols[i * 128 + base0 + __popcll(m1 & lt)] = j1;
  if (lane == 0) cnt[i] = base0 + __popcll(m1);
}

// ---------------------------------------------------------------------------
// 2) QKV GEMM: C[4096,3072] = xbf @ wqkvT^T. 128x128 tile, BK=32 ping-pong
//    dbuf (single barrier per step). Conflict-free chunk swizzle (64B rows):
//    phys chunk = logical ^ ((row>>1)&3). XCD-swizzled grid (bm == xcd mod 8).
//    Q output is pre-scaled by 0.125*log2(e) so attn can use exp2 directly.
// ---------------------------------------------------------------------------
__global__ __launch_bounds__(256) void gemm_qkv(
    const u16* __restrict__ A, const u16* __restrict__ Bt,
    u16* __restrict__ oq, u16* __restrict__ okk, u16* __restrict__ ov) {
  __shared__ u16 smem[16896];             // 4x4096 dbuf; epilogue 128x132
  u16* bA0 = smem;
  u16* bB0 = smem + 4096;
  u16* bA1 = smem + 8192;
  u16* bB1 = smem + 12288;
  const int K = 1024;
  int tid = threadIdx.x, lane = tid & 63, wave = tid >> 6;
  int quad = lane >> 4, l16 = lane & 15;
  int wr = wave >> 1, wc = wave & 1;
  int d = blockIdx.x;                     // 0..767
  int xcd = d & 7, rest = d >> 3;
  int bm = xcd + (rest & 3) * 8;
  int bn = rest >> 2;
  int bm0 = bm * 128, bn0 = bn * 128;

  f32x4 acc[4][4];
  #pragma unroll
  for (int i = 0; i < 4; i++)
    #pragma unroll
    for (int j = 0; j < 4; j++) acc[i][j] = (f32x4){0.f, 0.f, 0.f, 0.f};

  int srow = lane >> 2;                   // 0..15 row within 16-row DMA group
  // conflict-free swizzle: phys slot p at row r holds logical chunk p^((r>>1)&3)
  int schunk = ((lane & 3) ^ ((lane >> 3) & 3)) * 8;  // staged global 16B chunk
  int phys = (quad ^ ((l16 >> 1) & 3)) * 8;           // reader's physical chunk

  auto stage = [&](u16* dA, u16* dB, int k0) {
    #pragma unroll
    for (int r = 0; r < 2; r++) {
      int row = wave * 32 + r * 16;
      gload_lds16(A  + (size_t)(bm0 + row + srow) * K + k0 + schunk, dA + row * 32);
      gload_lds16(Bt + (size_t)(bn0 + row + srow) * K + k0 + schunk, dB + row * 32);
    }
  };
  auto compute = [&](const u16* cA, const u16* cB) {
    bf8 af[4], bfr[4];
    #pragma unroll
    for (int i = 0; i < 4; i++)
      af[i] = *(const bf8*)(cA + (wr * 64 + i * 16 + l16) * 32 + phys);
    #pragma unroll
    for (int j = 0; j < 4; j++)
      bfr[j] = *(const bf8*)(cB + (wc * 64 + j * 16 + l16) * 32 + phys);
    #pragma unroll
    for (int i = 0; i < 4; i++)
      #pragma unroll
      for (int j = 0; j < 4; j++)
        acc[i][j] = MFMA_BF16(af[i], bfr[j], acc[i][j]);
  };

  stage(bA0, bB0, 0);
  for (int k0 = 0; k0 < K; k0 += 64) {
    __syncthreads();                      // drains DMA into buf0; reads of buf1 done
    if (k0 + 32 < K) stage(bA1, bB1, k0 + 32);
    compute(bA0, bB0);
    __syncthreads();                      // drains DMA into buf1; reads of buf0 done
    if (k0 + 64 < K) stage(bA0, bB0, k0 + 64);
    compute(bA1, bB1);
  }

  int which = bn0 >> 10;                  // WG-uniform: 0=Q 1=K 2=V
  if (which == 2) {
    // V blocked [bh][jb][d 64][n 16]; lane's 4 acc values are n-contiguous
    #pragma unroll
    for (int j = 0; j < 4; j++) {
      int c = bn0 + wc * 64 + j * 16 + l16;
      int h = (c & 1023) >> 6, dd = c & 63;
      #pragma unroll
      for (int i = 0; i < 4; i++) {
        int r0 = bm0 + wr * 64 + i * 16;
        int b = r0 >> 11, nn0 = r0 & 2047, jb = nn0 >> 4;
        u16* dst = ov + ((size_t)((b * NH + h) * NBLK + jb) * DHD + dd) * 16 + quad * 4;
        *(uint2*)dst = make_uint2(pack2bf(acc[i][j][0], acc[i][j][1]),
                                  pack2bf(acc[i][j][2], acc[i][j][3]));
      }
    }
  } else {
    u16* dstbase = (which == 0) ? oq : okk;
    // fold softmax scale * log2(e) into Q (attn then uses exp2f directly)
    float m = (which == 0) ? 0.18033688f : 1.0f;
    __syncthreads();                      // last compute's LDS reads done before reuse
    // write phase: col-major buffer smem[col*132 + row]
    #pragma unroll
    for (int j = 0; j < 4; j++) {
      int col = wc * 64 + j * 16 + l16;
      #pragma unroll
      for (int i = 0; i < 4; i++) {
        int row = wr * 64 + i * 16 + quad * 4;
        *(uint2*)&smem[col * 132 + row] =
            make_uint2(pack2bf(acc[i][j][0] * m, acc[i][j][1] * m),
                       pack2bf(acc[i][j][2] * m, acc[i][j][3] * m));
      }
    }
    __syncthreads();
    int r = tid >> 1, half = tid & 1;
    int rglob = bm0 + r;
    int b = rglob >> 11, nn = rglob & 2047;
    int h = ((bn0 & 1023) >> 6) + half;
    #pragma unroll
    for (int j = 0; j < 4; j++) {
      union { u16 t[16]; uint4 q[2]; } tv;
      #pragma unroll
      for (int dd = 0; dd < 16; dd++)
        tv.t[dd] = smem[(half * 64 + j * 16 + dd) * 132 + r];
      u16* dst = dstbase + ((size_t)(b * NH + h) * SEQ + nn) * DHD + j * 16;
      *(uint4*)(dst) = tv.q[0];
      *(uint4*)(dst + 8) = tv.q[1];
    }
  }
}

// ---------------------------------------------------------------------------
// 3) out GEMM: out[4096,1024] = aout @ woutT^T + bias. 128Mx64N tile, BK=32
//    ping-pong dbuf, XCD-swizzled grid. Same conflict-free chunk swizzle.
// ---------------------------------------------------------------------------
__global__ __launch_bounds__(256) void gemm_out(
    const u16* __restrict__ A, const u16* __restrict__ Bt,
    float* __restrict__ of, const float* __restrict__ bias) {
  __shared__ u16 smem[12288];             // A0 4096 | B0 2048 | A1 4096 | B1 2048
  u16* bA0 = smem;
  u16* bB0 = smem + 4096;
  u16* bA1 = smem + 6144;
  u16* bB1 = smem + 10240;
  const int K = 1024, N = 1024;
  int tid = threadIdx.x, lane = tid & 63, wave = tid >> 6;
  int quad = lane >> 4, l16 = lane & 15;
  int wr = wave >> 1, wc = wave & 1;
  int d = blockIdx.x;                     // 0..511
  int xcd = d & 7, slot = d >> 3;
  int bm = xcd * 4 + (slot & 3);
  int bn = slot >> 2;
  int bm0 = bm * 128, bn0 = bn * 64;

  f32x4 acc[4][2];
  #pragma unroll
  for (int i = 0; i < 4; i++)
    #pragma unroll
    for (int j = 0; j < 2; j++) acc[i][j] = (f32x4){0.f, 0.f, 0.f, 0.f};

  int srow = lane >> 2;
  int schunk = ((lane & 3) ^ ((lane >> 3) & 3)) * 8;
  int phys = (quad ^ ((l16 >> 1) & 3)) * 8;

  auto stage = [&](u16* dA, u16* dB, int k0) {
    #pragma unroll
    for (int r = 0; r < 2; r++) {
      int row = wave * 32 + r * 16;
      gload_lds16(A + (size_t)(bm0 + row + srow) * K + k0 + schunk, dA + row * 32);
    }
    int brow = wave * 16;                 // 64 B rows: one instr per wave
    gload_lds16(Bt + (size_t)(bn0 + brow + srow) * K + k0 + schunk, dB + brow * 32);
  };
  auto compute = [&](const u16* cA, const u16* cB) {
    bf8 af[4], bfr[2];
    #pragma unroll
    for (int i = 0; i < 4; i++)
      af[i] = *(const bf8*)(cA + (wr * 64 + i * 16 + l16) * 32 + phys);
    #pragma unroll
    for (int j = 0; j < 2; j++)
      bfr[j] = *(const bf8*)(cB + (wc * 32 + j * 16 + l16) * 32 + phys);
    #pragma unroll
    for (int i = 0; i < 4; i++)
      #pragma unroll
      for (int j = 0; j < 2; j++)
        acc[i][j] = MFMA_BF16(af[i], bfr[j], acc[i][j]);
  };

  stage(bA0, bB0, 0);
  for (int k0 = 0; k0 < K; k0 += 64) {
    __syncthreads();
    if (k0 + 32 < K) stage(bA1, bB1, k0 + 32);
    compute(bA0, bB0);
    __syncthreads();
    if (k0 + 64 < K) stage(bA0, bB0, k0 + 64);
    compute(bA1, bB1);
  }

  #pragma unroll
  for (int j = 0; j < 2; j++) {
    int c = bn0 + wc * 32 + j * 16 + l16;
    float bv = bias[c];
    #pragma unroll
    for (int i = 0; i < 4; i++) {
      int rbase = bm0 + wr * 64 + i * 16 + quad * 4;
      #pragma unroll
      for (int ii = 0; ii < 4; ii++)
        of[(size_t)(rbase + ii) * N + c] = acc[i][j][ii] + bv;
    }
  }
}

// ---------------------------------------------------------------------------
// 4) block-sparse flash attention, S^T form, fixed-max softmax, depth-2
//    pair prefetch. ONE q-block per WAVE (no split, no combine, no barriers).
//    1024 WGs x 4 waves; qb = 127 - slot (longest lists first). XCD placement:
//    blk&7 owns 4 bh -> that head's K/V stays in its L2.
//    R14: reverted to the R9 block — LDS pbuf P^T permute (same-wave in-order
//    DS pipe, no barrier) + rotate prefetch pipeline. Keeps cvt_pk packs,
//    exp2 softmax (Q pre-scaled), setprio around MFMA clusters.
// ---------------------------------------------------------------------------
__global__ __launch_bounds__(256) void attn_sparse(
    const u16* __restrict__ q, const u16* __restrict__ k, const u16* __restrict__ vblk,
    const int* __restrict__ cnt, const int* __restrict__ cols,
    u16* __restrict__ aout) {
  __shared__ u32 pbuf[4][320];        // per-wave P permute, stride 20 u32
  int wave = threadIdx.x >> 6, lane = threadIdx.x & 63;
  int quad = lane >> 4, l16 = lane & 15;
  int blk = blockIdx.x;               // 0..1023
  int xcd = blk & 7, rest = blk >> 3; // rest 0..127
  int bh = xcd * 4 + (rest & 3);      // 4 heads per XCD
  int strip = rest >> 2;              // 0..31
  int qb = 127 - (strip * 4 + wave);  // longest lists first; 1 qb per wave
  u32* pbw = pbuf[wave];

  const u16* qp = q + ((size_t)bh * SEQ + qb * 16) * DHD + l16 * DHD + quad * 8;
  bf8 qa0 = *(const bf8*)(qp);
  bf8 qa1 = *(const bf8*)(qp + 32);

  float l_i = 0.f;
  f32x4 o[4];
  #pragma unroll
  for (int t = 0; t < 4; t++) o[t] = (f32x4){0.f, 0.f, 0.f, 0.f};

  int count = cnt[qb];
  const int* mc = cols + qb * NBLK;

  bf8 bufA[8], bufB[8];
  int ja0 = 0, ja1 = 0, jb0b = 0, jb1b = 0;
  bool hvA = false, hvB = false;

  auto ldpair = [&](int p, bf8* kv, int& o0, int& o1, bool& ohv) {
    o0 = mc[p];
    ohv = (p + 1 < count);
    o1 = ohv ? mc[p + 1] : o0;
    const u16* kp0 = k + ((size_t)bh * SEQ + o0 * 16) * DHD + l16 * DHD + quad * 8;
    kv[0] = *(const bf8*)(kp0); kv[1] = *(const bf8*)(kp0 + 32);
    const u16* kp1 = k + ((size_t)bh * SEQ + o1 * 16) * DHD + l16 * DHD + quad * 8;
    kv[2] = *(const bf8*)(kp1); kv[3] = *(const bf8*)(kp1 + 32);
    int jq = (quad < 2) ? o0 : o1;
    const u16* vp = vblk + (size_t)(bh * NBLK + jq) * 1024 + l16 * 16 + (quad & 1) * 8;
    kv[4] = *(const bf8*)(vp);
    kv[5] = *(const bf8*)(vp + 256);
    kv[6] = *(const bf8*)(vp + 512);
    kv[7] = *(const bf8*)(vp + 768);
  };

  ldpair(0, bufA, ja0, ja1, hvA);     // count >= 1 always (diagonal block)
  if (2 < count) ldpair(2, bufB, jb0b, jb1b, hvB);

  for (int p = 0; p < count; p += 2) {
    __builtin_amdgcn_s_setprio(1);
    f32x4 S0 = (f32x4){0.f, 0.f, 0.f, 0.f};
    S0 = MFMA_BF16(bufA[0], qa0, S0);
    S0 = MFMA_BF16(bufA[1], qa1, S0);
    f32x4 S1 = (f32x4){0.f, 0.f, 0.f, 0.f};
    S1 = MFMA_BF16(bufA[2], qa0, S1);
    S1 = MFMA_BF16(bufA[3], qa1, S1);
    __builtin_amdgcn_s_setprio(0);

    // fixed-max softmax: Q was pre-scaled by 0.125*log2(e) -> p = 2^S
    float e0[4], e1[4];
    #pragma unroll
    for (int r = 0; r < 4; r++) {
      int kl = quad * 4 + r;
      float s0 = S0[r];
      if (ja0 == qb && kl > l16) s0 = -1e38f;
      float s1 = hvA ? S1[r] : -1e38f;
      if (hvA && ja1 == qb && kl > l16) s1 = -1e38f;
      e0[r] = exp2f(s0);
      e1[r] = exp2f(s1);
      l_i += e0[r] + e1[r];
    }

    // P^T (C-layout) -> B-frag via per-wave LDS permute (in-order DS pipe,
    // no barrier needed). Packs are single v_cvt_pk_bf16_f32 each.
    *(uint2*)(&pbw[l16 * 20 + quad * 2]) =
        make_uint2(pack2bf(e0[0], e0[1]), pack2bf(e0[2], e0[3]));
    *(uint2*)(&pbw[l16 * 20 + 8 + quad * 2]) =
        make_uint2(pack2bf(e1[0], e1[1]), pack2bf(e1[2], e1[3]));
    union { uint4 w; bf8 v; } pf;
    pf.w = *(const uint4*)(&pbw[l16 * 20 + quad * 4]);

    // O^T += V^T · P^T
    __builtin_amdgcn_s_setprio(1);
    o[0] = MFMA_BF16(bufA[4], pf.v, o[0]);
    o[1] = MFMA_BF16(bufA[5], pf.v, o[1]);
    o[2] = MFMA_BF16(bufA[6], pf.v, o[2]);
    o[3] = MFMA_BF16(bufA[7], pf.v, o[3]);
    __builtin_amdgcn_s_setprio(0);

    // rotate prefetch pipeline
    #pragma unroll
    for (int z = 0; z < 8; z++) bufA[z] = bufB[z];
    ja0 = jb0b; ja1 = jb1b; hvA = hvB;
    if (p + 4 < count) ldpair(p + 4, bufB, jb0b, jb1b, hvB);
  }

  // epilogue: reduce l across quads, normalize, store (wave-private)
  float l = l_i;
  l += __shfl_xor(l, 16);
  l += __shfl_xor(l, 32);
  float inv = 1.0f / l;
  int b = bh >> 4, h = bh & 15;
  int n = qb * 16 + l16;
  u16* dst = aout + ((size_t)b * SEQ + n) * DIM + h * DHD;
  #pragma unroll
  for (int t = 0; t < 4; t++) {
    *(uint2*)(dst + t * 16 + quad * 4) =
        make_uint2(pack2bf(o[t][0] * inv, o[t][1] * inv),
                   pack2bf(o[t][2] * inv, o[t][3] * inv));
  }
}

// ---------------------------------------------------------------------------
// launch
// ---------------------------------------------------------------------------
extern "C" void kernel_launch(void* const* d_in, const int* in_sizes, int n_in,
                              void* d_out, int out_size, void* d_ws, size_t ws_size,
                              hipStream_t stream) {
  const float* x      = (const float*)d_in[0];
  const float* w_qkv  = (const float*)d_in[1];
  const float* w_out  = (const float*)d_in[2];
  const float* b_out  = (const float*)d_in[3];
  const unsigned char* layout = (const unsigned char*)d_in[4];
  float* out = (float*)d_out;

  char* ws = (char*)d_ws;
  u16* xbf   = (u16*)(ws);                 // [4096][1024]        8 MB
  u16* wqkvT = (u16*)(ws + (8u  << 20));   // [3072][1024]        6 MB
  u16* woutT = (u16*)(ws + (14u << 20) + (512u << 10)); // [1024][1024] 2 MB
  u16* qB    = (u16*)(ws + (17u << 20));   // [32][2048][64]      8 MB
  u16* kB    = (u16*)(ws + (25u << 20));   // 8 MB
  u16* vblk  = (u16*)(ws + (33u << 20));   // [32][128][64][16]   8 MB
  u16* aout  = (u16*)(ws + (41u << 20));   // [4096][1024]        8 MB
  int* cnt   = (int*)(ws + (49u << 20));
  int* cols  = (int*)(ws + (49u << 20) + 4096);

  prep<<<3104, 256, 0, stream>>>(x, xbf, w_qkv, wqkvT, w_out, woutT,
                                 layout, cnt, cols);
  gemm_qkv<<<768, 256, 0, stream>>>(xbf, wqkvT, qB, kB, vblk);
  attn_sparse<<<1024, 256, 0, stream>>>(qB, kB, vblk, cnt, cols, aout);
  gemm_out<<<512, 256, 0, stream>>>(aout, woutT, out, b_out);
}

// Round 8
// 163.272 us; speedup vs baseline: 1.0152x; 1.0152x over previous
//
#include <hip/hip_runtime.h>
#include <cstdint>
#include <cstddef>

// ---------------------------------------------------------------------------
// SparseAttention (DeepSpeed-style block-sparse causal attention)
//   x[2,2048,1024] @ w_qkv[1024,3072] -> q,k [bh][n][d], v blocked (bf16)
//   block-sparse flash attention (16x16 blocks, layout[128,128], causal)
//   attn_out[4096,1024] @ w_out[1024,1024] + b_out -> out (fp32)
// R15: champion config restored (R13: conflict-free LDS chunk swizzle GEMMs +
//      permlane attn, measured 164.4 us; R14 A/B showed pbuf attn slightly
//      worse). One probe: global stage base pointers hand-hoisted out of the
//      K-loop in both GEMMs (kills per-call 64-bit mul addr chains if the
//      compiler hadn't strength-reduced them). Byte-identical addresses.
// ---------------------------------------------------------------------------

typedef short bf8 __attribute__((ext_vector_type(8)));   // 8 bf16 payloads (4 VGPRs)
typedef float f32x4 __attribute__((ext_vector_type(4)));
typedef unsigned short u16;
typedef unsigned int u32;

#define MFMA_BF16(a, b, c) __builtin_amdgcn_mfma_f32_16x16x32_bf16((a), (b), (c), 0, 0, 0)

constexpr int SEQ = 2048;
constexpr int NH = 16;
constexpr int DHD = 64;
constexpr int NBLK = 128;
constexpr int DIM = 1024;

// hw packed fp32->bf16 convert (RNE), a -> low 16, b -> high 16
__device__ __forceinline__ u32 pack2bf(float a, float b) {
  u32 r;
  asm("v_cvt_pk_bf16_f32 %0, %1, %2" : "=v"(r) : "v"(a), "v"(b));
  return r;
}
__device__ __forceinline__ void gload_lds16(const u16* g, u16* l) {
  auto gp = (const __attribute__((address_space(1))) u16*)(g);
  auto lp = (__attribute__((address_space(3))) u16*)(l);
  __builtin_amdgcn_global_load_lds(gp, lp, 16, 0, 0);
}

// ---------------------------------------------------------------------------
// 1) fused prep: [0,2048) convert x; [2048,2816) transpose w_qkv;
//    [2816,3072) transpose w_out; [3072,3104) build layout lists.
// ---------------------------------------------------------------------------
__global__ __launch_bounds__(256) void prep(
    const float* __restrict__ x, u16* __restrict__ xbf,
    const float* __restrict__ wqkv, u16* __restrict__ wqkvT,
    const float* __restrict__ wout, u16* __restrict__ woutT,
    const unsigned char* __restrict__ lay,
    int* __restrict__ cnt, int* __restrict__ cols) {
  __shared__ u16 tile[64][72];
  int bid = blockIdx.x;
  int t = threadIdx.x;

  if (bid < 2048) {                       // ---- convert x fp32 -> bf16
    int idx = (bid * 256 + t) * 8;
    float4 a = *(const float4*)(x + idx);
    float4 b = *(const float4*)(x + idx + 4);
    *(uint4*)(xbf + idx) = make_uint4(pack2bf(a.x, a.y), pack2bf(a.z, a.w),
                                      pack2bf(b.x, b.y), pack2bf(b.z, b.w));
    return;
  }
  bid -= 2048;
  if (bid < 768 + 256) {                  // ---- weight transposes
    const float* in; u16* out; int C, bx, by;
    if (bid < 768) { in = wqkv; out = wqkvT; C = 3072; bx = bid % 48; by = bid / 48; }
    else { int r = bid - 768; in = wout; out = woutT; C = 1024; bx = r % 16; by = r / 16; }
    const int R = 1024;
    int c0 = bx * 64, r0 = by * 64;
    int rr = t >> 4, cc = (t & 15) * 4;
    #pragma unroll
    for (int p = 0; p < 64; p += 16) {
      float4 v = *(const float4*)(in + (size_t)(r0 + rr + p) * C + c0 + cc);
      *(u32*)&tile[rr + p][cc + 0] = pack2bf(v.x, v.y);
      *(u32*)&tile[rr + p][cc + 2] = pack2bf(v.z, v.w);
    }
    __syncthreads();
    int oc = t >> 3, orr = (t & 7) * 8;
    #pragma unroll
    for (int p = 0; p < 64; p += 32) {
      u16 tmp[8];
      #pragma unroll
      for (int qy = 0; qy < 8; qy++) tmp[qy] = tile[orr + qy][oc + p];
      u16* dst = out + (size_t)(c0 + oc + p) * R + r0 + orr;
      *(ushort4*)(dst)     = make_ushort4(tmp[0], tmp[1], tmp[2], tmp[3]);
      *(ushort4*)(dst + 4) = make_ushort4(tmp[4], tmp[5], tmp[6], tmp[7]);
    }
    return;
  }
  bid -= 1024;                            // ---- build_lists: 32 blocks x 4 waves
  int wave = t >> 6, lane = t & 63;
  int i = bid * 4 + wave;                 // block row
  const uint4* l4 = (const uint4*)lay;
  u32 acc = 0;
  #pragma unroll
  for (int it = 0; it < 16; it++) {
    uint4 v = l4[it * 64 + lane];
    acc |= ((v.x | v.y | v.z | v.w) & 0xFFFFFF00u);
  }
  bool as_int32 = (__ballot(acc != 0) == 0ULL);  // int32-encoded 0/1 detection
  const int* li = (const int*)lay;
  int j0 = lane, j1 = lane + 64;
  bool p0 = (j0 <= i) && (as_int32 ? (li[i * 128 + j0] != 0) : (lay[i * 128 + j0] != 0));
  bool p1 = (j1 <= i) && (as_int32 ? (li[i * 128 + j1] != 0) : (lay[i * 128 + j1] != 0));
  unsigned long long m0 = __ballot(p0), m1 = __ballot(p1);
  unsigned long long lt = (1ULL << lane) - 1ULL;
  int base0 = __popcll(m0);
  if (p0) cols[i * 128 + __popcll(m0 & lt)] = j0;
  if (p1) cols[i * 128 + base0 + __popcll(m1 & lt)] = j1;
  if (lane == 0) cnt[i] = base0 + __popcll(m1);
}

// ---------------------------------------------------------------------------
// 2) QKV GEMM: C[4096,3072] = xbf @ wqkvT^T. 128x128 tile, BK=32 ping-pong
//    dbuf (single barrier per step). Conflict-free chunk swizzle (64B rows):
//    phys chunk = logical ^ ((row>>1)&3). XCD-swizzled grid (bm == xcd mod 8).
//    Stage base pointers hoisted out of the K-loop (addr = base + k0).
//    Q output is pre-scaled by 0.125*log2(e) so attn can use exp2 directly.
// ---------------------------------------------------------------------------
__global__ __launch_bounds__(256) void gemm_qkv(
    const u16* __restrict__ A, const u16* __restrict__ Bt,
    u16* __restrict__ oq, u16* __restrict__ okk, u16* __restrict__ ov) {
  __shared__ u16 smem[16896];             // 4x4096 dbuf; epilogue 128x132
  u16* bA0 = smem;
  u16* bB0 = smem + 4096;
  u16* bA1 = smem + 8192;
  u16* bB1 = smem + 12288;
  const int K = 1024;
  int tid = threadIdx.x, lane = tid & 63, wave = tid >> 6;
  int quad = lane >> 4, l16 = lane & 15;
  int wr = wave >> 1, wc = wave & 1;
  int d = blockIdx.x;                     // 0..767
  int xcd = d & 7, rest = d >> 3;
  int bm = xcd + (rest & 3) * 8;
  int bn = rest >> 2;
  int bm0 = bm * 128, bn0 = bn * 128;

  f32x4 acc[4][4];
  #pragma unroll
  for (int i = 0; i < 4; i++)
    #pragma unroll
    for (int j = 0; j < 4; j++) acc[i][j] = (f32x4){0.f, 0.f, 0.f, 0.f};

  int srow = lane >> 2;                   // 0..15 row within 16-row DMA group
  // conflict-free swizzle: phys slot p at row r holds logical chunk p^((r>>1)&3)
  int schunk = ((lane & 3) ^ ((lane >> 3) & 3)) * 8;  // staged global 16B chunk
  int phys = (quad ^ ((l16 >> 1) & 3)) * 8;           // reader's physical chunk

  // hoisted global stage bases (row = wave*32 [+16], col = schunk)
  const u16* gA0 = A  + (size_t)(bm0 + wave * 32 + srow) * K + schunk;
  const u16* gB0 = Bt + (size_t)(bn0 + wave * 32 + srow) * K + schunk;
  int dA0 = wave * 1024;                  // (wave*32)*32 u16 LDS offset

  auto stage = [&](u16* dA, u16* dB, int k0) {
    gload_lds16(gA0 + k0,          dA + dA0);
    gload_lds16(gB0 + k0,          dB + dA0);
    gload_lds16(gA0 + 16 * K + k0, dA + dA0 + 512);
    gload_lds16(gB0 + 16 * K + k0, dB + dA0 + 512);
  };
  auto compute = [&](const u16* cA, const u16* cB) {
    bf8 af[4], bfr[4];
    #pragma unroll
    for (int i = 0; i < 4; i++)
      af[i] = *(const bf8*)(cA + (wr * 64 + i * 16 + l16) * 32 + phys);
    #pragma unroll
    for (int j = 0; j < 4; j++)
      bfr[j] = *(const bf8*)(cB + (wc * 64 + j * 16 + l16) * 32 + phys);
    #pragma unroll
    for (int i = 0; i < 4; i++)
      #pragma unroll
      for (int j = 0; j < 4; j++)
        acc[i][j] = MFMA_BF16(af[i], bfr[j], acc[i][j]);
  };

  stage(bA0, bB0, 0);
  for (int k0 = 0; k0 < K; k0 += 64) {
    __syncthreads();                      // drains DMA into buf0; reads of buf1 done
    if (k0 + 32 < K) stage(bA1, bB1, k0 + 32);
    compute(bA0, bB0);
    __syncthreads();                      // drains DMA into buf1; reads of buf0 done
    if (k0 + 64 < K) stage(bA0, bB0, k0 + 64);
    compute(bA1, bB1);
  }

  int which = bn0 >> 10;                  // WG-uniform: 0=Q 1=K 2=V
  if (which == 2) {
    // V blocked [bh][jb][d 64][n 16]; lane's 4 acc values are n-contiguous
    #pragma unroll
    for (int j = 0; j < 4; j++) {
      int c = bn0 + wc * 64 + j * 16 + l16;
      int h = (c & 1023) >> 6, dd = c & 63;
      #pragma unroll
      for (int i = 0; i < 4; i++) {
        int r0 = bm0 + wr * 64 + i * 16;
        int b = r0 >> 11, nn0 = r0 & 2047, jb = nn0 >> 4;
        u16* dst = ov + ((size_t)((b * NH + h) * NBLK + jb) * DHD + dd) * 16 + quad * 4;
        *(uint2*)dst = make_uint2(pack2bf(acc[i][j][0], acc[i][j][1]),
                                  pack2bf(acc[i][j][2], acc[i][j][3]));
      }
    }
  } else {
    u16* dstbase = (which == 0) ? oq : okk;
    // fold softmax scale * log2(e) into Q (attn then uses exp2f directly)
    float m = (which == 0) ? 0.18033688f : 1.0f;
    __syncthreads();                      // last compute's LDS reads done before reuse
    // write phase: col-major buffer smem[col*132 + row]
    #pragma unroll
    for (int j = 0; j < 4; j++) {
      int col = wc * 64 + j * 16 + l16;
      #pragma unroll
      for (int i = 0; i < 4; i++) {
        int row = wr * 64 + i * 16 + quad * 4;
        *(uint2*)&smem[col * 132 + row] =
            make_uint2(pack2bf(acc[i][j][0] * m, acc[i][j][1] * m),
                       pack2bf(acc[i][j][2] * m, acc[i][j][3] * m));
      }
    }
    __syncthreads();
    int r = tid >> 1, half = tid & 1;
    int rglob = bm0 + r;
    int b = rglob >> 11, nn = rglob & 2047;
    int h = ((bn0 & 1023) >> 6) + half;
    #pragma unroll
    for (int j = 0; j < 4; j++) {
      union { u16 t[16]; uint4 q[2]; } tv;
      #pragma unroll
      for (int dd = 0; dd < 16; dd++)
        tv.t[dd] = smem[(half * 64 + j * 16 + dd) * 132 + r];
      u16* dst = dstbase + ((size_t)(b * NH + h) * SEQ + nn) * DHD + j * 16;
      *(uint4*)(dst) = tv.q[0];
      *(uint4*)(dst + 8) = tv.q[1];
    }
  }
}

// ---------------------------------------------------------------------------
// 3) out GEMM: out[4096,1024] = aout @ woutT^T + bias. 128Mx64N tile, BK=32
//    ping-pong dbuf, XCD-swizzled grid. Conflict-free chunk swizzle; hoisted
//    stage bases.
// ---------------------------------------------------------------------------
__global__ __launch_bounds__(256) void gemm_out(
    const u16* __restrict__ A, const u16* __restrict__ Bt,
    float* __restrict__ of, const float* __restrict__ bias) {
  __shared__ u16 smem[12288];             // A0 4096 | B0 2048 | A1 4096 | B1 2048
  u16* bA0 = smem;
  u16* bB0 = smem + 4096;
  u16* bA1 = smem + 6144;
  u16* bB1 = smem + 10240;
  const int K = 1024, N = 1024;
  int tid = threadIdx.x, lane = tid & 63, wave = tid >> 6;
  int quad = lane >> 4, l16 = lane & 15;
  int wr = wave >> 1, wc = wave & 1;
  int d = blockIdx.x;                     // 0..511
  int xcd = d & 7, slot = d >> 3;
  int bm = xcd * 4 + (slot & 3);
  int bn = slot >> 2;
  int bm0 = bm * 128, bn0 = bn * 64;

  f32x4 acc[4][2];
  #pragma unroll
  for (int i = 0; i < 4; i++)
    #pragma unroll
    for (int j = 0; j < 2; j++) acc[i][j] = (f32x4){0.f, 0.f, 0.f, 0.f};

  int srow = lane >> 2;
  int schunk = ((lane & 3) ^ ((lane >> 3) & 3)) * 8;
  int phys = (quad ^ ((l16 >> 1) & 3)) * 8;

  const u16* gA0 = A  + (size_t)(bm0 + wave * 32 + srow) * K + schunk;
  const u16* gB0 = Bt + (size_t)(bn0 + wave * 16 + srow) * K + schunk;
  int dA0 = wave * 1024;
  int dB0 = wave * 512;                   // (wave*16)*32 u16

  auto stage = [&](u16* dA, u16* dB, int k0) {
    gload_lds16(gA0 + k0,          dA + dA0);
    gload_lds16(gA0 + 16 * K + k0, dA + dA0 + 512);
    gload_lds16(gB0 + k0,          dB + dB0);
  };
  auto compute = [&](const u16* cA, const u16* cB) {
    bf8 af[4], bfr[2];
    #pragma unroll
    for (int i = 0; i < 4; i++)
      af[i] = *(const bf8*)(cA + (wr * 64 + i * 16 + l16) * 32 + phys);
    #pragma unroll
    for (int j = 0; j < 2; j++)
      bfr[j] = *(const bf8*)(cB + (wc * 32 + j * 16 + l16) * 32 + phys);
    #pragma unroll
    for (int i = 0; i < 4; i++)
      #pragma unroll
      for (int j = 0; j < 2; j++)
        acc[i][j] = MFMA_BF16(af[i], bfr[j], acc[i][j]);
  };

  stage(bA0, bB0, 0);
  for (int k0 = 0; k0 < K; k0 += 64) {
    __syncthreads();
    if (k0 + 32 < K) stage(bA1, bB1, k0 + 32);
    compute(bA0, bB0);
    __syncthreads();
    if (k0 + 64 < K) stage(bA0, bB0, k0 + 64);
    compute(bA1, bB1);
  }

  #pragma unroll
  for (int j = 0; j < 2; j++) {
    int c = bn0 + wc * 32 + j * 16 + l16;
    float bv = bias[c];
    #pragma unroll
    for (int i = 0; i < 4; i++) {
      int rbase = bm0 + wr * 64 + i * 16 + quad * 4;
      #pragma unroll
      for (int ii = 0; ii < 4; ii++)
        of[(size_t)(rbase + ii) * N + c] = acc[i][j][ii] + bv;
    }
  }
}

// ---------------------------------------------------------------------------
// 4) block-sparse flash attention, S^T form, fixed-max softmax, depth-2
//    pair prefetch. ONE q-block per WAVE (no split, no combine, no barriers).
//    1024 WGs x 4 waves; qb = 127 - slot (longest lists first). XCD placement:
//    blk&7 owns 4 bh -> that head's K/V stays in its L2.
//    P^T redistribution via 4 permlane swaps (register-only, no LDS);
//    2x-unrolled A/B buffer loop. (champion R13 version)
// ---------------------------------------------------------------------------
__global__ __launch_bounds__(256) void attn_sparse(
    const u16* __restrict__ q, const u16* __restrict__ k, const u16* __restrict__ vblk,
    const int* __restrict__ cnt, const int* __restrict__ cols,
    u16* __restrict__ aout) {
  int wave = threadIdx.x >> 6, lane = threadIdx.x & 63;
  int quad = lane >> 4, l16 = lane & 15;
  int blk = blockIdx.x;               // 0..1023
  int xcd = blk & 7, rest = blk >> 3; // rest 0..127
  int bh = xcd * 4 + (rest & 3);      // 4 heads per XCD
  int strip = rest >> 2;              // 0..31
  int qb = 127 - (strip * 4 + wave);  // longest lists first; 1 qb per wave

  const u16* qp = q + ((size_t)bh * SEQ + qb * 16) * DHD + l16 * DHD + quad * 8;
  bf8 qa0 = *(const bf8*)(qp);
  bf8 qa1 = *(const bf8*)(qp + 32);

  float l_i = 0.f;
  f32x4 o[4];
  #pragma unroll
  for (int t = 0; t < 4; t++) o[t] = (f32x4){0.f, 0.f, 0.f, 0.f};

  int count = cnt[qb];
  const int* mc = cols + qb * NBLK;

  bf8 bufA[8], bufB[8];
  int jA0 = 0, jA1 = 0, jB0 = 0, jB1 = 0;
  bool hA = false, hB = false;

  auto ldpair = [&](int p, bf8* kv, int& o0, int& o1, bool& ohv) {
    o0 = mc[p];
    ohv = (p + 1 < count);
    o1 = ohv ? mc[p + 1] : o0;
    const u16* kp0 = k + ((size_t)bh * SEQ + o0 * 16) * DHD + l16 * DHD + quad * 8;
    kv[0] = *(const bf8*)(kp0); kv[1] = *(const bf8*)(kp0 + 32);
    const u16* kp1 = k + ((size_t)bh * SEQ + o1 * 16) * DHD + l16 * DHD + quad * 8;
    kv[2] = *(const bf8*)(kp1); kv[3] = *(const bf8*)(kp1 + 32);
    int jq = (quad < 2) ? o0 : o1;
    const u16* vp = vblk + (size_t)(bh * NBLK + jq) * 1024 + l16 * 16 + (quad & 1) * 8;
    kv[4] = *(const bf8*)(vp);
    kv[5] = *(const bf8*)(vp + 256);
    kv[6] = *(const bf8*)(vp + 512);
    kv[7] = *(const bf8*)(vp + 768);
  };

  // process one K-block pair held in buf (j0/j1/hv are its block columns)
  auto process = [&](const bf8* buf, int j0, int j1, bool hv) {
    __builtin_amdgcn_s_setprio(1);
    f32x4 S0 = (f32x4){0.f, 0.f, 0.f, 0.f};
    S0 = MFMA_BF16(buf[0], qa0, S0);
    S0 = MFMA_BF16(buf[1], qa1, S0);
    f32x4 S1 = (f32x4){0.f, 0.f, 0.f, 0.f};
    S1 = MFMA_BF16(buf[2], qa0, S1);
    S1 = MFMA_BF16(buf[3], qa1, S1);
    __builtin_amdgcn_s_setprio(0);

    // fixed-max softmax: Q was pre-scaled by 0.125*log2(e) -> p = 2^S
    float e0[4], e1[4];
    #pragma unroll
    for (int r = 0; r < 4; r++) {
      int kl = quad * 4 + r;
      float s0 = S0[r];
      if (j0 == qb && kl > l16) s0 = -1e38f;
      float s1 = hv ? S1[r] : -1e38f;
      if (hv && j1 == qb && kl > l16) s1 = -1e38f;
      e0[r] = exp2f(s0);
      e1[r] = exp2f(s1);
      l_i += e0[r] + e1[r];
    }

    // P^T (C-layout) -> B-frag: pure-register cross-quad exchange.
    u32 a0 = pack2bf(e0[0], e0[1]);
    u32 a1 = pack2bf(e0[2], e0[3]);
    u32 a2 = pack2bf(e1[0], e1[1]);
    u32 a3 = pack2bf(e1[2], e1[3]);
    asm("v_permlane32_swap_b32 %0, %1" : "+v"(a0), "+v"(a2));
    asm("v_permlane32_swap_b32 %0, %1" : "+v"(a1), "+v"(a3));
    asm("v_permlane16_swap_b32 %0, %1" : "+v"(a0), "+v"(a2));
    asm("v_permlane16_swap_b32 %0, %1" : "+v"(a1), "+v"(a3));
    union { uint4 w; bf8 v; } pf;
    pf.w = make_uint4(a0, a1, a2, a3);

    // O^T += V^T · P^T
    __builtin_amdgcn_s_setprio(1);
    o[0] = MFMA_BF16(buf[4], pf.v, o[0]);
    o[1] = MFMA_BF16(buf[5], pf.v, o[1]);
    o[2] = MFMA_BF16(buf[6], pf.v, o[2]);
    o[3] = MFMA_BF16(buf[7], pf.v, o[3]);
    __builtin_amdgcn_s_setprio(0);
  };

  ldpair(0, bufA, jA0, jA1, hA);      // count >= 1 always (diagonal block)
  if (2 < count) ldpair(2, bufB, jB0, jB1, hB);

  for (int p = 0; p < count; p += 4) {
    process(bufA, jA0, jA1, hA);
    if (p + 4 < count) ldpair(p + 4, bufA, jA0, jA1, hA);
    if (p + 2 < count) process(bufB, jB0, jB1, hB);
    if (p + 6 < count) ldpair(p + 6, bufB, jB0, jB1, hB);
  }

  // epilogue: reduce l across quads, normalize, store (wave-private)
  float l = l_i;
  l += __shfl_xor(l, 16);
  l += __shfl_xor(l, 32);
  float inv = 1.0f / l;
  int b = bh >> 4, h = bh & 15;
  int n = qb * 16 + l16;
  u16* dst = aout + ((size_t)b * SEQ + n) * DIM + h * DHD;
  #pragma unroll
  for (int t = 0; t < 4; t++) {
    *(uint2*)(dst + t * 16 + quad * 4) =
        make_uint2(pack2bf(o[t][0] * inv, o[t][1] * inv),
                   pack2bf(o[t][2] * inv, o[t][3] * inv));
  }
}

// ---------------------------------------------------------------------------
// launch
// ---------------------------------------------------------------------------
extern "C" void kernel_launch(void* const* d_in, const int* in_sizes, int n_in,
                              void* d_out, int out_size, void* d_ws, size_t ws_size,
                              hipStream_t stream) {
  const float* x      = (const float*)d_in[0];
  const float* w_qkv  = (const float*)d_in[1];
  const float* w_out  = (const float*)d_in[2];
  const float* b_out  = (const float*)d_in[3];
  const unsigned char* layout = (const unsigned char*)d_in[4];
  float* out = (float*)d_out;

  char* ws = (char*)d_ws;
  u16* xbf   = (u16*)(ws);                 // [4096][1024]        8 MB
  u16* wqkvT = (u16*)(ws + (8u  << 20));   // [3072][1024]        6 MB
  u16* woutT = (u16*)(ws + (14u << 20) + (512u << 10)); // [1024][1024] 2 MB
  u16* qB    = (u16*)(ws + (17u << 20));   // [32][2048][64]      8 MB
  u16* kB    = (u16*)(ws + (25u << 20));   // 8 MB
  u16* vblk  = (u16*)(ws + (33u << 20));   // [32][128][64][16]   8 MB
  u16* aout  = (u16*)(ws + (41u << 20));   // [4096][1024]        8 MB
  int* cnt   = (int*)(ws + (49u << 20));
  int* cols  = (int*)(ws + (49u << 20) + 4096);

  prep<<<3104, 256, 0, stream>>>(x, xbf, w_qkv, wqkvT, w_out, woutT,
                                 layout, cnt, cols);
  gemm_qkv<<<768, 256, 0, stream>>>(xbf, wqkvT, qB, kB, vblk);
  attn_sparse<<<1024, 256, 0, stream>>>(qB, kB, vblk, cnt, cols, aout);
  gemm_out<<<512, 256, 0, stream>>>(aout, woutT, out, b_out);
}